// Round 5
// baseline (493.403 us; speedup 1.0000x reference)
//
#include <hip/hip_runtime.h>
#include <hip/hip_bf16.h>
#include <hip/hip_cooperative_groups.h>

namespace cg = cooperative_groups;

// GraphAE: pseudo == 0 => only W[0] of the 8 spline matrices matters.
// Linearization: mean(h[src])@W2_0 == mean(h[src]@W2_0) -> project before gather.
// Round 14:
//  - CSR build (prep-hist + partition + fill, 3 serial launches, ~110us
//    inferred) merged into ONE cooperative kernel with grid.sync():
//      A: packs + x->bf16 + dst histogram (full 4096-wave grid)
//      B: partition into 128-node buckets (391), packed (d&127)<<16|src
//      C: per-bucket node ordering (391 blocks x 512 thr)
//    512 blocks x 512 thr, __launch_bounds__(512,4) -> guaranteed 2/CU
//    co-residency; 16.5KB LDS union.
//  - agg/gemm kernels unchanged from R13 (proven).
//
// Verified MFMA layouts (guide §3): A[m=lane&15][k=(lane>>4)*8+j],
// B[k=(lane>>4)*8+j][n=lane&15], D[row=(lane>>4)*4+r][col=lane&15].

#define THREADS 256

typedef __attribute__((ext_vector_type(8))) short bf16x8;   // 8 bf16 = 4 VGPRs
typedef __attribute__((ext_vector_type(4))) float f32x4;    // acc

__device__ __forceinline__ float bf2f(unsigned short u) {
    unsigned v = ((unsigned)u) << 16;
    return __builtin_bit_cast(float, v);
}
__device__ __forceinline__ unsigned short f2bf(float f) {
    __hip_bfloat16 h = __float2bfloat16(f);   // RNE
    return __builtin_bit_cast(unsigned short, h);
}
__device__ __forceinline__ void acc8(float* f, uint4 v) {
    f[0] += bf2f((unsigned short)v.x); f[1] += bf2f((unsigned short)(v.x >> 16));
    f[2] += bf2f((unsigned short)v.y); f[3] += bf2f((unsigned short)(v.y >> 16));
    f[4] += bf2f((unsigned short)v.z); f[5] += bf2f((unsigned short)(v.z >> 16));
    f[6] += bf2f((unsigned short)v.w); f[7] += bf2f((unsigned short)(v.w >> 16));
}

// ---------------- weight pack ----------------
// Pack fp32 W (eff. K x NOUT) into MFMA B-frag layout bf16:
// dst[(((s*NB + j)*64 + lane)*8 + i] = W[s*32 + (lane>>4)*8 + i][j*16 + (lane&15)]
__device__ __forceinline__ void pack_one(unsigned short* dst,
                                         const float* W0, const float* W1,
                                         int NB, int ksplit, int colsplit,
                                         int ld0, int ld1, int t) {
    int i = t & 7, lane = (t >> 3) & 63, rest = t >> 9;
    int j = rest % NB, s = rest / NB;
    int k = s * 32 + ((lane >> 4) << 3) + i;
    int c = (j << 4) + (lane & 15);
    float v;
    if (c >= colsplit)    v = W1[(size_t)k * ld1 + (c - colsplit)];
    else if (k >= ksplit) v = W1[(size_t)(k - ksplit) * ld1 + c];
    else                  v = W0[(size_t)k * ld0 + c];
    dst[t] = f2bf(v);
}

#define BIG (1 << 30)

// ---------------- cooperative CSR kernel ----------------
// Phase A: packs + x->bf16 + dst histogram -> bcnt[512] (128-node buckets)
// Phase B: partition edges into buckets, epack = (d&127)<<16 | src
// Phase C: per-bucket ordering -> esrc grouped by node, offs/invd
__global__ __launch_bounds__(512, 4) void csr_kernel(
    const float* __restrict__ W1g, const float* __restrict__ root1,
    const float* __restrict__ W2g, const float* __restrict__ root2,
    const float* __restrict__ dw1, const float* __restrict__ dw2,
    const float* __restrict__ x,
    const int* __restrict__ srcv, const int* __restrict__ dstv,
    int* __restrict__ bcnt, int* __restrict__ bcur,
    int* __restrict__ epack, int* __restrict__ offs,
    float* __restrict__ invd, int* __restrict__ esrc,
    unsigned short* __restrict__ Pb1, unsigned short* __restrict__ Pb2,
    unsigned short* __restrict__ Pd1, unsigned short* __restrict__ Pd2,
    unsigned short* __restrict__ ab1,
    int n, int E) {
    __shared__ int S[4096];       // 16 KB union, carved per phase
    cg::grid_group grid = cg::this_grid();
    const int T = 512;
    const int t = threadIdx.x;
    const int nblk = gridDim.x;

    // ---- phase A: packs + convert (grid-stride) ----
    int ntask = 98304 + n * 16;
    for (int u = (int)blockIdx.x * T + t; u < ntask; u += nblk * T) {
        if (u < 32768) {
            pack_one(Pb1, W1g, root1, 16, 64, BIG, 256, 256, u);
        } else if (u < 65536) {
            pack_one(Pb2, W2g, root2, 8, BIG, 64, 64, 64, u - 32768);
        } else if (u < 81920) {
            pack_one(Pd1, dw1, dw1, 16, BIG, BIG, 256, 256, u - 65536);
        } else if (u < 98304) {
            pack_one(Pd2, dw2, dw2, 4, BIG, BIG, 64, 64, u - 81920);
        } else {
            int v_ = u - 98304;
            int row = v_ >> 4, c4 = (v_ & 15) * 4;
            float4 v = *(const float4*)(x + (size_t)row * 64 + c4);
            unsigned lo = (unsigned)f2bf(v.x) | ((unsigned)f2bf(v.y) << 16);
            unsigned hi = (unsigned)f2bf(v.z) | ((unsigned)f2bf(v.w) << 16);
            uint2 o; o.x = lo; o.y = hi;
            *(uint2*)(ab1 + (size_t)row * 128 + 64 + c4) = o;
        }
    }
    // ---- phase A: histogram ----
    {
        int* hist = S;
        hist[t] = 0;
        __syncthreads();
        int per = (E + nblk - 1) / nblk;
        int e0 = blockIdx.x * per, e1 = min(E, e0 + per);
        for (int e = e0 + t; e < e1; e += T)
            atomicAdd(&hist[dstv[e] >> 7], 1);
        __syncthreads();
        int h = hist[t];
        if (h) atomicAdd(&bcnt[t], h);
    }
    __threadfence();
    grid.sync();

    // ---- phase B: partition into 128-node buckets ----
    {
        int* hist = S; int* base = S + 512; int* lcur = S + 1024; int* bb = S + 1536;
        hist[t] = 0; lcur[t] = 0;
        __syncthreads();
        int per = (E + nblk - 1) / nblk;
        int e0 = blockIdx.x * per, e1 = min(E, e0 + per);
        int myd[4], mys[4];
        int cnt = 0;
        for (int e = e0 + t, i = 0; e < e1; e += T, ++i) {
            myd[i] = dstv[e]; mys[i] = srcv[e]; cnt = i + 1;
            atomicAdd(&hist[myd[i] >> 7], 1);
        }
        int cb = bcnt[t];
        bb[t] = cb;
        __syncthreads();
        for (int off = 1; off < 512; off <<= 1) {
            int xv = (t >= off) ? bb[t - off] : 0;
            __syncthreads();
            bb[t] += xv;
            __syncthreads();
        }
        int h = hist[t];
        if (h) base[t] = (bb[t] - cb) + atomicAdd(&bcur[t], h);
        __syncthreads();
        for (int i = 0; i < cnt; ++i) {
            int b = myd[i] >> 7;
            int p = atomicAdd(&lcur[b], 1);
            epack[base[b] + p] = ((myd[i] & 127) << 16) | mys[i];
        }
    }
    __threadfence();
    grid.sync();

    // ---- phase C: per-bucket node ordering ----
    {
        int nbk = (n + 127) >> 7;
        int b = blockIdx.x;
        if (b < nbk) {
            int* sb = S; int* nh = S + 512; int* loff = S + 640;
            int* ncur = S + 768; int* stage = S + 1024;   // 3072 cap
            sb[t] = bcnt[t];
            __syncthreads();
            for (int off = 1; off < 512; off <<= 1) {
                int xv = (t >= off) ? sb[t - off] : 0;
                __syncthreads();
                sb[t] += xv;
                __syncthreads();
            }
            int ebase = b ? sb[b - 1] : 0;
            int ecount = sb[b] - ebase;
            if (b == 0 && t == 0) offs[n] = sb[511];
            if (t < 128) nh[t] = 0;
            __syncthreads();
            for (int i = t; i < ecount; i += T)
                atomicAdd(&nh[epack[ebase + i] >> 16], 1);
            __syncthreads();
            int v = 0;
            if (t < 128) { v = nh[t]; loff[t] = v; }
            __syncthreads();
            for (int off = 1; off < 128; off <<= 1) {
                int xv = (t >= off && t < 128) ? loff[t - off] : 0;
                __syncthreads();
                if (t < 128) loff[t] += xv;
                __syncthreads();
            }
            if (t < 128) {
                int ex = loff[t] - v;
                loff[t] = ex;
                int node = (b << 7) + t;
                if (node < n) {
                    offs[node] = ebase + ex;
                    invd[node] = 1.0f / (float)max(v, 1);
                }
                ncur[t] = 0;
            }
            __syncthreads();
            bool useLds = (ecount <= 3072);
            for (int i = t; i < ecount; i += T) {
                int p = epack[ebase + i];
                int dl = p >> 16;
                int pos = atomicAdd(&ncur[dl], 1);
                int g = loff[dl] + pos;       // bucket-local slot
                int sv = p & 0xFFFF;
                if (useLds) stage[g] = sv;
                else        esrc[ebase + g] = sv;
            }
            __syncthreads();
            if (useLds)
                for (int i = t; i < ecount; i += T) esrc[ebase + i] = stage[i];
        }
    }
}

// ---------------- gathers: 16B/lane, 8 edges per wave-instr, 16-edge unroll ----
// lane = slot(8) x c(8); lane loads features [c*8, c*8+8) of edge (j+slot).
// agg1 = mean(x[src]): reads ab1 cols 64:128, writes ab1 cols 0:64.
__global__ void agg_x4(unsigned short* __restrict__ ab1, const int* __restrict__ esrc,
                       const int* __restrict__ offs, const float* __restrict__ invd,
                       int n) {
    int node = blockIdx.x * 4 + (threadIdx.x >> 6);
    if (node >= n) return;
    int l = threadIdx.x & 63;
    int slot = l >> 3, c = l & 7;
    const unsigned short* xb = ab1 + 64 + c * 8;
    int s = offs[node], e = offs[node + 1];
    float a0[8] = {}, a1[8] = {};
    int j = s;
    for (; j + 16 <= e; j += 16) {
        int i0 = esrc[j + slot], i1 = esrc[j + 8 + slot];
        uint4 v0 = *(const uint4*)(xb + (size_t)i0 * 128);
        uint4 v1 = *(const uint4*)(xb + (size_t)i1 * 128);
        acc8(a0, v0); acc8(a1, v1);
    }
    if (j + 8 <= e) {
        int i0 = esrc[j + slot];
        uint4 v0 = *(const uint4*)(xb + (size_t)i0 * 128);
        acc8(a0, v0);
        j += 8;
    }
    if (slot < e - j) {
        int i0 = esrc[j + slot];
        uint4 v0 = *(const uint4*)(xb + (size_t)i0 * 128);
        acc8(a1, v0);
    }
    float r[8];
#pragma unroll
    for (int k = 0; k < 8; ++k) {
        r[k] = a0[k] + a1[k];
        r[k] += __shfl_xor(r[k], 8);
        r[k] += __shfl_xor(r[k], 16);
        r[k] += __shfl_xor(r[k], 32);
    }
    if (slot == 0) {
        float iv = invd[node];
        unsigned p0 = (unsigned)f2bf(r[0] * iv) | ((unsigned)f2bf(r[1] * iv) << 16);
        unsigned p1 = (unsigned)f2bf(r[2] * iv) | ((unsigned)f2bf(r[3] * iv) << 16);
        unsigned p2 = (unsigned)f2bf(r[4] * iv) | ((unsigned)f2bf(r[5] * iv) << 16);
        unsigned p3 = (unsigned)f2bf(r[6] * iv) | ((unsigned)f2bf(r[7] * iv) << 16);
        uint4 o; o.x = p0; o.y = p1; o.z = p2; o.w = p3;
        *(uint4*)(ab1 + (size_t)node * 128 + c * 8) = o;
    }
}

// z = mean(hw[src]) + hroot + b2 ; hwroot N x 128 bf16 (0:64 hw, 64:128 hroot)
__global__ void agg_z4(const unsigned short* __restrict__ hwroot,
                       const int* __restrict__ esrc, const int* __restrict__ offs,
                       const float* __restrict__ invd, const float* __restrict__ b2,
                       unsigned short* __restrict__ z, int n) {
    int node = blockIdx.x * 4 + (threadIdx.x >> 6);
    if (node >= n) return;
    int l = threadIdx.x & 63;
    int slot = l >> 3, c = l & 7;
    const unsigned short* hb = hwroot + c * 8;
    int s = offs[node], e = offs[node + 1];
    float a0[8] = {}, a1[8] = {};
    int j = s;
    for (; j + 16 <= e; j += 16) {
        int i0 = esrc[j + slot], i1 = esrc[j + 8 + slot];
        uint4 v0 = *(const uint4*)(hb + (size_t)i0 * 128);
        uint4 v1 = *(const uint4*)(hb + (size_t)i1 * 128);
        acc8(a0, v0); acc8(a1, v1);
    }
    if (j + 8 <= e) {
        int i0 = esrc[j + slot];
        uint4 v0 = *(const uint4*)(hb + (size_t)i0 * 128);
        acc8(a0, v0);
        j += 8;
    }
    if (slot < e - j) {
        int i0 = esrc[j + slot];
        uint4 v0 = *(const uint4*)(hb + (size_t)i0 * 128);
        acc8(a1, v0);
    }
    float r[8];
#pragma unroll
    for (int k = 0; k < 8; ++k) {
        r[k] = a0[k] + a1[k];
        r[k] += __shfl_xor(r[k], 8);
        r[k] += __shfl_xor(r[k], 16);
        r[k] += __shfl_xor(r[k], 32);
    }
    if (slot == 0) {
        float iv = invd[node];
        uint4 hr = *(const uint4*)(hwroot + (size_t)node * 128 + 64 + c * 8);
        float4 bA = *(const float4*)(b2 + c * 8);
        float4 bB = *(const float4*)(b2 + c * 8 + 4);
        float v0 = r[0] * iv + bf2f((unsigned short)hr.x) + bA.x;
        float v1 = r[1] * iv + bf2f((unsigned short)(hr.x >> 16)) + bA.y;
        float v2 = r[2] * iv + bf2f((unsigned short)hr.y) + bA.z;
        float v3 = r[3] * iv + bf2f((unsigned short)(hr.y >> 16)) + bA.w;
        float v4 = r[4] * iv + bf2f((unsigned short)hr.z) + bB.x;
        float v5 = r[5] * iv + bf2f((unsigned short)(hr.z >> 16)) + bB.y;
        float v6 = r[6] * iv + bf2f((unsigned short)hr.w) + bB.z;
        float v7 = r[7] * iv + bf2f((unsigned short)(hr.w >> 16)) + bB.w;
        unsigned p0 = (unsigned)f2bf(v0) | ((unsigned)f2bf(v1) << 16);
        unsigned p1 = (unsigned)f2bf(v2) | ((unsigned)f2bf(v3) << 16);
        unsigned p2 = (unsigned)f2bf(v4) | ((unsigned)f2bf(v5) << 16);
        unsigned p3 = (unsigned)f2bf(v6) | ((unsigned)f2bf(v7) << 16);
        uint4 o; o.x = p0; o.y = p1; o.z = p2; o.w = p3;
        *(uint4*)(z + (size_t)node * 64 + c * 8) = o;
    }
}

// ---------------- fused double-GEMM ----------------
// Stage 1: T = relu(A @ Wp1 + bias1)  (A: n x K1 bf16, T: 64 x 256 tile in LDS)
// Stage 2: C = T @ Wp2 (+ bias2)      (C: n x (NBW2*64))
template <int K1, int NBW2, bool OUTBF>
__global__ __launch_bounds__(256) void gemm_fused(
    const unsigned short* __restrict__ A,
    const unsigned short* __restrict__ Bp1, const float* __restrict__ bias1,
    const unsigned short* __restrict__ Bp2, const float* __restrict__ bias2,
    void* __restrict__ Cv, int n)
{
    constexpr int KS1 = K1 / 32;
    constexpr int N2 = NBW2 * 64;
    constexpr int NB2 = NBW2 * 4;
    __shared__ unsigned short ht[64][264];

    const int m0 = blockIdx.x * 64;
    const int lane = threadIdx.x & 63;
    const int w = threadIdx.x >> 6;
    const int quad = lane >> 4;
    const int l16 = lane & 15;

    // ---- stage 1 ----
    {
        f32x4 acc[4][4] = {};
        const unsigned short* Arow = A + (size_t)(m0 + l16) * K1 + quad * 8;
        for (int s = 0; s < KS1; ++s) {
            bf16x8 a[4];
#pragma unroll
            for (int mb = 0; mb < 4; ++mb)
                a[mb] = *(const bf16x8*)(Arow + (size_t)mb * 16 * K1 + s * 32);
#pragma unroll
            for (int jn = 0; jn < 4; ++jn) {
                int j = w * 4 + jn;
                bf16x8 b = *(const bf16x8*)(Bp1 + ((size_t)(s * 16 + j) * 64 + lane) * 8);
#pragma unroll
                for (int mb = 0; mb < 4; ++mb)
                    acc[mb][jn] = __builtin_amdgcn_mfma_f32_16x16x32_bf16(a[mb], b, acc[mb][jn], 0, 0, 0);
            }
        }
#pragma unroll
        for (int jn = 0; jn < 4; ++jn) {
            int col = (w * 4 + jn) * 16 + l16;
            float bv = bias1[col];
#pragma unroll
            for (int mb = 0; mb < 4; ++mb)
#pragma unroll
                for (int r = 0; r < 4; ++r) {
                    int row = mb * 16 + quad * 4 + r;
                    ht[row][col] = f2bf(fmaxf(acc[mb][jn][r] + bv, 0.f));
                }
        }
    }
    __syncthreads();

    // ---- stage 2 ----
    {
        f32x4 acc[4][NBW2] = {};
        for (int s = 0; s < 8; ++s) {
            bf16x8 a[4];
#pragma unroll
            for (int mb = 0; mb < 4; ++mb)
                a[mb] = *(const bf16x8*)&ht[mb * 16 + l16][s * 32 + quad * 8];
#pragma unroll
            for (int jn = 0; jn < NBW2; ++jn) {
                int j = w * NBW2 + jn;
                bf16x8 b = *(const bf16x8*)(Bp2 + ((size_t)(s * NB2 + j) * 64 + lane) * 8);
#pragma unroll
                for (int mb = 0; mb < 4; ++mb)
                    acc[mb][jn] = __builtin_amdgcn_mfma_f32_16x16x32_bf16(a[mb], b, acc[mb][jn], 0, 0, 0);
            }
        }
#pragma unroll
        for (int jn = 0; jn < NBW2; ++jn) {
            int col = (w * NBW2 + jn) * 16 + l16;
            float bv = bias2 ? bias2[col] : 0.f;
#pragma unroll
            for (int mb = 0; mb < 4; ++mb)
#pragma unroll
                for (int r = 0; r < 4; ++r) {
                    int row = m0 + mb * 16 + quad * 4 + r;
                    if (row < n) {
                        float v = acc[mb][jn][r] + bv;
                        if (OUTBF)
                            ((unsigned short*)Cv)[(size_t)row * N2 + col] = f2bf(v);
                        else
                            ((float*)Cv)[(size_t)row * N2 + col] = v;
                    }
                }
        }
    }
}

extern "C" void kernel_launch(void* const* d_in, const int* in_sizes, int n_in,
                              void* d_out, int out_size, void* d_ws, size_t ws_size,
                              hipStream_t stream) {
    const float* x      = (const float*)d_in[0];
    const int*   ei     = (const int*)d_in[1];
    const float* W1g    = (const float*)d_in[2];   // (8,64,256): [0] = first 16384
    const float* root1  = (const float*)d_in[3];
    const float* b1     = (const float*)d_in[4];
    const float* W2g    = (const float*)d_in[5];   // (8,256,64): [0] = first 16384
    const float* root2  = (const float*)d_in[6];
    const float* b2     = (const float*)d_in[7];
    const float* dw1    = (const float*)d_in[8];
    const float* db1    = (const float*)d_in[9];
    const float* dw2    = (const float*)d_in[10];
    const float* db2    = (const float*)d_in[11];
    float* out = (float*)d_out;

    const int N = in_sizes[0] / 64;
    const int E = in_sizes[1] / 2;
    const int Npad = N + 64;
    const int* srcv = ei;
    const int* dstv = ei + E;

    char* ws = (char*)d_ws;
    auto alloc = [&](size_t bytes) -> void* {
        void* p = (void*)ws;
        ws += (bytes + 255) & ~(size_t)255;
        return p;
    };
    int*   bcnt   = (int*)alloc(2048);               // per-bucket counts (512 pad)
    int*   bcur   = (int*)alloc(2048);               // partition cursors
    int*   offs   = (int*)alloc((size_t)(N + 1) * 4);
    float* invd   = (float*)alloc((size_t)N * 4);
    int*   esrc   = (int*)alloc((size_t)E * 4);
    int*   epack  = (int*)alloc((size_t)E * 4);
    unsigned short* Pb1 = (unsigned short*)alloc(32768 * 2);
    unsigned short* Pb2 = (unsigned short*)alloc(32768 * 2);
    unsigned short* Pd1 = (unsigned short*)alloc(16384 * 2);
    unsigned short* Pd2 = (unsigned short*)alloc(16384 * 2);
    unsigned short* ab1    = (unsigned short*)alloc((size_t)Npad * 128 * 2);  // [agg1 | xb]
    unsigned short* hwroot = (unsigned short*)alloc((size_t)Npad * 128 * 2);
    unsigned short* z      = (unsigned short*)alloc((size_t)Npad * 64 * 2);

    hipMemsetAsync(bcnt, 0, 4096, stream);           // bcnt + bcur (adjacent)

    int gb = (N + 63) / 64;
    int Nv = N, Ev = E;

    // cooperative CSR: histogram -> partition -> per-bucket ordering
    void* ka[] = {
        (void*)&W1g, (void*)&root1, (void*)&W2g, (void*)&root2,
        (void*)&dw1, (void*)&dw2, (void*)&x, (void*)&srcv, (void*)&dstv,
        (void*)&bcnt, (void*)&bcur, (void*)&epack, (void*)&offs, (void*)&invd,
        (void*)&esrc, (void*)&Pb1, (void*)&Pb2, (void*)&Pd1, (void*)&Pd2,
        (void*)&ab1, (void*)&Nv, (void*)&Ev };
    hipLaunchCooperativeKernel((void*)csr_kernel, dim3(512), dim3(512),
                               ka, 0, stream);

    // layer 1 agg + fused [L1 GEMM -> L2 projection]
    agg_x4<<<(N + 3) / 4, THREADS, 0, stream>>>(ab1, esrc, offs, invd, N);
    gemm_fused<128, 2, true><<<gb, 256, 0, stream>>>(ab1, Pb1, b1, Pb2, nullptr, hwroot, N);
    // layer 2 gather + epilogue
    agg_z4<<<(N + 3) / 4, THREADS, 0, stream>>>(hwroot, esrc, offs, invd, b2, z, N);
    // fused decoder [dec1 -> dec2]
    gemm_fused<64, 1, false><<<gb, 256, 0, stream>>>(z, Pd1, db1, Pd2, db2, out, N);
}

// Round 6
// 297.366 us; speedup vs baseline: 1.6592x; 1.6592x over previous
//
#include <hip/hip_runtime.h>
#include <hip/hip_bf16.h>

// GraphAE: pseudo == 0 => only W[0] of the 8 spline matrices matters.
// Linearization: mean(h[src])@W2_0 == mean(h[src]@W2_0) -> project before gather.
// Round 15:
//  - R14 cooperative mega-kernel reverted (306us: spin-wait + VGPR-capped).
//  - Base = R13 (199us). Two changes:
//    (a) aggs re-gridded XCD-local: slice = blockIdx&7 -> each XCD gathers
//        only a 16B column slice (800KB, L2-resident) instead of random
//        128B rows from a 12.8MB table (LLC/HBM). lane = slot(16)x node(4),
//        per-lane degree loop, shfl_xor 4/8/16/32 reduce.
//    (b) prep histogram widened 4096->2048 edges/block (391 blocks).
//
// Verified MFMA layouts (guide §3): A[m=lane&15][k=(lane>>4)*8+j],
// B[k=(lane>>4)*8+j][n=lane&15], D[row=(lane>>4)*4+r][col=lane&15].

#define THREADS 256

typedef __attribute__((ext_vector_type(8))) short bf16x8;   // 8 bf16 = 4 VGPRs
typedef __attribute__((ext_vector_type(4))) float f32x4;    // acc

__device__ __forceinline__ float bf2f(unsigned short u) {
    unsigned v = ((unsigned)u) << 16;
    return __builtin_bit_cast(float, v);
}
__device__ __forceinline__ unsigned short f2bf(float f) {
    __hip_bfloat16 h = __float2bfloat16(f);   // RNE
    return __builtin_bit_cast(unsigned short, h);
}
__device__ __forceinline__ void acc8(float* f, uint4 v) {
    f[0] += bf2f((unsigned short)v.x); f[1] += bf2f((unsigned short)(v.x >> 16));
    f[2] += bf2f((unsigned short)v.y); f[3] += bf2f((unsigned short)(v.y >> 16));
    f[4] += bf2f((unsigned short)v.z); f[5] += bf2f((unsigned short)(v.z >> 16));
    f[6] += bf2f((unsigned short)v.w); f[7] += bf2f((unsigned short)(v.w >> 16));
}

// ---------------- weight pack ----------------
// Pack fp32 W (eff. K x NOUT) into MFMA B-frag layout bf16:
// dst[(((s*NB + j)*64 + lane)*8 + i] = W[s*32 + (lane>>4)*8 + i][j*16 + (lane&15)]
__device__ __forceinline__ void pack_one(unsigned short* dst,
                                         const float* W0, const float* W1,
                                         int NB, int ksplit, int colsplit,
                                         int ld0, int ld1, int t) {
    int i = t & 7, lane = (t >> 3) & 63, rest = t >> 9;
    int j = rest % NB, s = rest / NB;
    int k = s * 32 + ((lane >> 4) << 3) + i;
    int c = (j << 4) + (lane & 15);
    float v;
    if (c >= colsplit)    v = W1[(size_t)k * ld1 + (c - colsplit)];
    else if (k >= ksplit) v = W1[(size_t)(k - ksplit) * ld1 + c];
    else                  v = W0[(size_t)k * ld0 + c];
    dst[t] = f2bf(v);
}

#define BIG (1 << 30)

// prep: weight packs + x->bf16 (vectorized) + bucket histogram (edge blocks)
__global__ void prep_kernel(const float* __restrict__ W1g, const float* __restrict__ root1,
                            const float* __restrict__ W2g, const float* __restrict__ root2,
                            const float* __restrict__ dw1, const float* __restrict__ dw2,
                            const float* __restrict__ x, const int* __restrict__ dstv,
                            int* __restrict__ bcnt,
                            unsigned short* __restrict__ Pb1,   // 128x256
                            unsigned short* __restrict__ Pb2,   // 256x128
                            unsigned short* __restrict__ Pd1,   // 64x256
                            unsigned short* __restrict__ Pd2,   // 256x64
                            unsigned short* __restrict__ ab1,   // N x 128, x -> cols 64:128
                            int n, int E, int pb_pack) {
    if ((int)blockIdx.x >= pb_pack) {
        __shared__ int hist[256];
        int t = threadIdx.x;
        hist[t] = 0;
        __syncthreads();
        int e0 = ((int)blockIdx.x - pb_pack) * 2048;
#pragma unroll
        for (int i = 0; i < 8; ++i) {
            int e = e0 + t + i * 256;
            if (e < E) atomicAdd(&hist[dstv[e] >> 8], 1);
        }
        __syncthreads();
        int h = hist[t];
        if (h) atomicAdd(&bcnt[t], h);
        return;
    }
    int t = blockIdx.x * blockDim.x + threadIdx.x;
    if (t < 32768) {
        pack_one(Pb1, W1g, root1, 16, 64, BIG, 256, 256, t);
    } else if (t < 65536) {
        pack_one(Pb2, W2g, root2, 8, BIG, 64, 64, 64, t - 32768);
    } else if (t < 81920) {
        pack_one(Pd1, dw1, dw1, 16, BIG, BIG, 256, 256, t - 65536);
    } else if (t < 98304) {
        pack_one(Pd2, dw2, dw2, 4, BIG, BIG, 64, 64, t - 81920);
    } else if (t < 98304 + n * 16) {
        int u = t - 98304;
        int row = u >> 4, c4 = (u & 15) * 4;
        float4 v = *(const float4*)(x + (size_t)row * 64 + c4);
        unsigned lo = (unsigned)f2bf(v.x) | ((unsigned)f2bf(v.y) << 16);
        unsigned hi = (unsigned)f2bf(v.z) | ((unsigned)f2bf(v.w) << 16);
        uint2 o; o.x = lo; o.y = hi;
        *(uint2*)(ab1 + (size_t)row * 128 + 64 + c4) = o;
    }
}

// Pass A: partition edges into buckets of 256 consecutive dst nodes.
// 512 threads x 2048 edges/block (391 blocks, 3128 waves) for latency hiding.
__global__ __launch_bounds__(512) void partition_edges(
    const int* __restrict__ src, const int* __restrict__ dst,
    const int* __restrict__ bcnt, int* __restrict__ bcur,
    int* __restrict__ epack, int E) {
    __shared__ int hist[256];
    __shared__ int base[256];
    __shared__ int lcur[256];
    __shared__ int bb[256];
    int t = threadIdx.x;
    if (t < 256) { hist[t] = 0; lcur[t] = 0; }
    __syncthreads();
    int e0 = blockIdx.x * 2048;
    int myd[4], mys[4];
#pragma unroll
    for (int i = 0; i < 4; ++i) {
        int e = e0 + t + i * 512;
        int d = (e < E) ? dst[e] : -1;
        mys[i] = (e < E) ? src[e] : 0;
        myd[i] = d;
        if (d >= 0) atomicAdd(&hist[d >> 8], 1);
    }
    // local exclusive scan of bcnt -> bucket bases (t<256 active)
    int cb = 0;
    if (t < 256) { cb = bcnt[t]; bb[t] = cb; }
    __syncthreads();
    for (int off = 1; off < 256; off <<= 1) {
        int xv = (t >= off && t < 256) ? bb[t - off] : 0;
        __syncthreads();
        if (t < 256) bb[t] += xv;
        __syncthreads();
    }
    if (t < 256) {
        int h = hist[t];
        if (h > 0) base[t] = (bb[t] - cb) + atomicAdd(&bcur[t], h);
    }
    __syncthreads();
#pragma unroll
    for (int i = 0; i < 4; ++i) {
        int d = myd[i];
        if (d >= 0) {
            int b = d >> 8;
            int p = atomicAdd(&lcur[b], 1);
            epack[base[b] + p] = ((d & 255) << 20) | mys[i];
        }
    }
}

// Pass B: one block (1024 threads, 16 waves) per 256-node bucket.
// Local per-node histogram + scan in LDS (emits offs and invd), then
// bucket-local ordering + coalesced esrc write.
__global__ __launch_bounds__(1024) void bucket_fill2(
    const int* __restrict__ epack, const int* __restrict__ bcnt,
    int* __restrict__ offs, float* __restrict__ invd,
    int* __restrict__ esrc, int N) {
    __shared__ int sb_[256];
    __shared__ int nh[256];
    __shared__ int loff[256];
    __shared__ int ncur[256];
    __shared__ int stage[8192];
    int b = blockIdx.x, t = threadIdx.x;
    int n0 = b << 8;
    // bucket base via local scan of bcnt
    int cb = 0;
    if (t < 256) { cb = bcnt[t]; sb_[t] = cb; }
    __syncthreads();
    for (int off = 1; off < 256; off <<= 1) {
        int xv = (t >= off && t < 256) ? sb_[t - off] : 0;
        __syncthreads();
        if (t < 256) sb_[t] += xv;
        __syncthreads();
    }
    int ebase = b ? sb_[b - 1] : 0;
    int ecount = sb_[b] - ebase;
    if (b == 0 && t == 0) offs[N] = sb_[255];
    if (t < 256) nh[t] = 0;
    __syncthreads();
    for (int i = t; i < ecount; i += 1024)
        atomicAdd(&nh[epack[ebase + i] >> 20], 1);
    __syncthreads();
    int v = 0;
    if (t < 256) { v = nh[t]; loff[t] = v; }
    __syncthreads();
    for (int off = 1; off < 256; off <<= 1) {
        int xv = (t >= off && t < 256) ? loff[t - off] : 0;
        __syncthreads();
        if (t < 256) loff[t] += xv;
        __syncthreads();
    }
    if (t < 256) {
        int ex = loff[t] - v;
        loff[t] = ex;
        int node = n0 + t;
        if (node < N) {
            offs[node] = ebase + ex;
            invd[node] = 1.0f / (float)max(v, 1);
        }
        ncur[t] = 0;
    }
    __syncthreads();
    bool useLds = (ecount <= 8192);
    for (int i = t; i < ecount; i += 1024) {
        int p = epack[ebase + i];
        int dl = p >> 20;
        int pos = atomicAdd(&ncur[dl], 1);
        int g = loff[dl] + pos;         // bucket-local slot
        int sv = p & 0xFFFFF;
        if (useLds) stage[g] = sv;
        else        esrc[ebase + g] = sv;
    }
    __syncthreads();
    if (useLds)
        for (int i = t; i < ecount; i += 1024) esrc[ebase + i] = stage[i];
}

// ---------------- XCD-local column-sliced gathers ----------------
// slice s = blockIdx & 7 owns 8 output cols [s*8, s*8+8) (16B). Consecutive
// blocks round-robin across XCDs, so XCD s only ever touches the 16B column
// slice of the gather table (50000 x 16B = 800KB -> L2-resident).
// Block: 32 nodes; wave w: nodes [w*8, w*8+8) as 2 quads of 4.
// lane: nsub = l&3 (node in quad), slot = l>>2 (edge slot, 16-wide).
// MODE 0: out = mean(x[src]) -> ab1 cols 0:64 (gather from cols 64:128)
// MODE 1: out = mean(hw[src]) + hroot + b2 -> z (gather hw cols 0:64)
template <int MODE>
__global__ __launch_bounds__(256) void agg_slice(
    const unsigned short* __restrict__ tbl,
    const int* __restrict__ esrc, const int* __restrict__ offs,
    const float* __restrict__ invd, const float* __restrict__ b2,
    const unsigned short* __restrict__ hwroot,
    unsigned short* __restrict__ outb, int n) {
    const int b = blockIdx.x;
    const int s = b & 7, grp = b >> 3;
    const int l = threadIdx.x & 63, w = threadIdx.x >> 6;
    const int nsub = l & 3, slot = l >> 2;
    const int OS = (MODE == 0) ? 128 : 64;
    const unsigned short* tb = tbl + ((MODE == 0) ? 64 : 0) + s * 8;

#pragma unroll
    for (int q = 0; q < 2; ++q) {
        int node = grp * 32 + w * 8 + q * 4 + nsub;
        bool valid = node < n;
        int s0 = valid ? offs[node] : 0;
        int e0 = valid ? offs[node + 1] : 0;
        float a[8] = {};
        int j = s0 + slot;
        while (__any(j < e0)) {
            if (j < e0) {
                int src = esrc[j];
                uint4 v = *(const uint4*)(tb + (size_t)src * 128);
                acc8(a, v);
            }
            j += 16;
        }
#pragma unroll
        for (int k = 0; k < 8; ++k) {
            a[k] += __shfl_xor(a[k], 4);
            a[k] += __shfl_xor(a[k], 8);
            a[k] += __shfl_xor(a[k], 16);
            a[k] += __shfl_xor(a[k], 32);
        }
        if (slot == 0 && valid) {
            float iv = invd[node];
            float v[8];
#pragma unroll
            for (int k = 0; k < 8; ++k) v[k] = a[k] * iv;
            if (MODE == 1) {
                uint4 hr = *(const uint4*)(hwroot + (size_t)node * 128 + 64 + s * 8);
                v[0] += bf2f((unsigned short)hr.x)         + b2[s * 8 + 0];
                v[1] += bf2f((unsigned short)(hr.x >> 16)) + b2[s * 8 + 1];
                v[2] += bf2f((unsigned short)hr.y)         + b2[s * 8 + 2];
                v[3] += bf2f((unsigned short)(hr.y >> 16)) + b2[s * 8 + 3];
                v[4] += bf2f((unsigned short)hr.z)         + b2[s * 8 + 4];
                v[5] += bf2f((unsigned short)(hr.z >> 16)) + b2[s * 8 + 5];
                v[6] += bf2f((unsigned short)hr.w)         + b2[s * 8 + 6];
                v[7] += bf2f((unsigned short)(hr.w >> 16)) + b2[s * 8 + 7];
            }
            unsigned p0 = (unsigned)f2bf(v[0]) | ((unsigned)f2bf(v[1]) << 16);
            unsigned p1 = (unsigned)f2bf(v[2]) | ((unsigned)f2bf(v[3]) << 16);
            unsigned p2 = (unsigned)f2bf(v[4]) | ((unsigned)f2bf(v[5]) << 16);
            unsigned p3 = (unsigned)f2bf(v[6]) | ((unsigned)f2bf(v[7]) << 16);
            uint4 o; o.x = p0; o.y = p1; o.z = p2; o.w = p3;
            *(uint4*)(outb + (size_t)node * OS + s * 8) = o;
        }
    }
}

// ---------------- fused double-GEMM ----------------
// Stage 1: T = relu(A @ Wp1 + bias1)  (A: n x K1 bf16, T: 64 x 256 tile in LDS)
// Stage 2: C = T @ Wp2 (+ bias2)      (C: n x (NBW2*64))
template <int K1, int NBW2, bool OUTBF>
__global__ __launch_bounds__(256) void gemm_fused(
    const unsigned short* __restrict__ A,
    const unsigned short* __restrict__ Bp1, const float* __restrict__ bias1,
    const unsigned short* __restrict__ Bp2, const float* __restrict__ bias2,
    void* __restrict__ Cv, int n)
{
    constexpr int KS1 = K1 / 32;
    constexpr int N2 = NBW2 * 64;
    constexpr int NB2 = NBW2 * 4;
    __shared__ unsigned short ht[64][264];

    const int m0 = blockIdx.x * 64;
    const int lane = threadIdx.x & 63;
    const int w = threadIdx.x >> 6;
    const int quad = lane >> 4;
    const int l16 = lane & 15;

    // ---- stage 1 ----
    {
        f32x4 acc[4][4] = {};
        const unsigned short* Arow = A + (size_t)(m0 + l16) * K1 + quad * 8;
        for (int s = 0; s < KS1; ++s) {
            bf16x8 a[4];
#pragma unroll
            for (int mb = 0; mb < 4; ++mb)
                a[mb] = *(const bf16x8*)(Arow + (size_t)mb * 16 * K1 + s * 32);
#pragma unroll
            for (int jn = 0; jn < 4; ++jn) {
                int j = w * 4 + jn;
                bf16x8 b = *(const bf16x8*)(Bp1 + ((size_t)(s * 16 + j) * 64 + lane) * 8);
#pragma unroll
                for (int mb = 0; mb < 4; ++mb)
                    acc[mb][jn] = __builtin_amdgcn_mfma_f32_16x16x32_bf16(a[mb], b, acc[mb][jn], 0, 0, 0);
            }
        }
#pragma unroll
        for (int jn = 0; jn < 4; ++jn) {
            int col = (w * 4 + jn) * 16 + l16;
            float bv = bias1[col];
#pragma unroll
            for (int mb = 0; mb < 4; ++mb)
#pragma unroll
                for (int r = 0; r < 4; ++r) {
                    int row = mb * 16 + quad * 4 + r;
                    ht[row][col] = f2bf(fmaxf(acc[mb][jn][r] + bv, 0.f));
                }
        }
    }
    __syncthreads();

    // ---- stage 2 ----
    {
        f32x4 acc[4][NBW2] = {};
        for (int s = 0; s < 8; ++s) {
            bf16x8 a[4];
#pragma unroll
            for (int mb = 0; mb < 4; ++mb)
                a[mb] = *(const bf16x8*)&ht[mb * 16 + l16][s * 32 + quad * 8];
#pragma unroll
            for (int jn = 0; jn < NBW2; ++jn) {
                int j = w * NBW2 + jn;
                bf16x8 b = *(const bf16x8*)(Bp2 + ((size_t)(s * NB2 + j) * 64 + lane) * 8);
#pragma unroll
                for (int mb = 0; mb < 4; ++mb)
                    acc[mb][jn] = __builtin_amdgcn_mfma_f32_16x16x32_bf16(a[mb], b, acc[mb][jn], 0, 0, 0);
            }
        }
#pragma unroll
        for (int jn = 0; jn < NBW2; ++jn) {
            int col = (w * NBW2 + jn) * 16 + l16;
            float bv = bias2 ? bias2[col] : 0.f;
#pragma unroll
            for (int mb = 0; mb < 4; ++mb)
#pragma unroll
                for (int r = 0; r < 4; ++r) {
                    int row = m0 + mb * 16 + quad * 4 + r;
                    if (row < n) {
                        float v = acc[mb][jn][r] + bv;
                        if (OUTBF)
                            ((unsigned short*)Cv)[(size_t)row * N2 + col] = f2bf(v);
                        else
                            ((float*)Cv)[(size_t)row * N2 + col] = v;
                    }
                }
        }
    }
}

extern "C" void kernel_launch(void* const* d_in, const int* in_sizes, int n_in,
                              void* d_out, int out_size, void* d_ws, size_t ws_size,
                              hipStream_t stream) {
    const float* x      = (const float*)d_in[0];
    const int*   ei     = (const int*)d_in[1];
    const float* W1g    = (const float*)d_in[2];   // (8,64,256): [0] = first 16384
    const float* root1  = (const float*)d_in[3];
    const float* b1     = (const float*)d_in[4];
    const float* W2g    = (const float*)d_in[5];   // (8,256,64): [0] = first 16384
    const float* root2  = (const float*)d_in[6];
    const float* b2     = (const float*)d_in[7];
    const float* dw1    = (const float*)d_in[8];
    const float* db1    = (const float*)d_in[9];
    const float* dw2    = (const float*)d_in[10];
    const float* db2    = (const float*)d_in[11];
    float* out = (float*)d_out;

    const int N = in_sizes[0] / 64;
    const int E = in_sizes[1] / 2;
    const int Npad = N + 64;
    const int* srcv = ei;
    const int* dstv = ei + E;

    char* ws = (char*)d_ws;
    auto alloc = [&](size_t bytes) -> void* {
        void* p = (void*)ws;
        ws += (bytes + 255) & ~(size_t)255;
        return p;
    };
    int*   bcnt   = (int*)alloc(1024);               // per-bucket counts (256)
    int*   bcur   = (int*)alloc(1024);               // 0-based bucket cursors
    int*   offs   = (int*)alloc((size_t)(N + 1) * 4);
    float* invd   = (float*)alloc((size_t)N * 4);
    int*   esrc   = (int*)alloc((size_t)E * 4);
    int*   epack  = (int*)alloc((size_t)E * 4);
    unsigned short* Pb1 = (unsigned short*)alloc(32768 * 2);
    unsigned short* Pb2 = (unsigned short*)alloc(32768 * 2);
    unsigned short* Pd1 = (unsigned short*)alloc(16384 * 2);
    unsigned short* Pd2 = (unsigned short*)alloc(16384 * 2);
    unsigned short* ab1    = (unsigned short*)alloc((size_t)Npad * 128 * 2);  // [agg1 | xb]
    unsigned short* hwroot = (unsigned short*)alloc((size_t)Npad * 128 * 2);
    unsigned short* z      = (unsigned short*)alloc((size_t)Npad * 64 * 2);

    hipMemsetAsync(bcnt, 0, 2048, stream);           // bcnt + bcur (adjacent)

    int gb = (N + 63) / 64;
    int nbkt = (N + 255) / 256;
    int pa = (E + 2047) / 2048;                      // hist blocks (widened)
    int pb_pack = (98304 + N * 16 + THREADS - 1) / THREADS;
    int ga = ((N + 31) / 32) * 8;                    // sliced agg grid (x8 XCD)

    // packs + x->bf16 + bucket histogram (one kernel, disjoint block ranges)
    prep_kernel<<<pb_pack + pa, THREADS, 0, stream>>>(
        W1g, root1, W2g, root2, dw1, dw2, x, dstv, bcnt,
        Pb1, Pb2, Pd1, Pd2, ab1, N, E, pb_pack);
    // bucket-level CSR (bases computed locally from bcnt in each kernel)
    partition_edges<<<pa, 512, 0, stream>>>(srcv, dstv, bcnt, bcur, epack, E);
    bucket_fill2<<<nbkt, 1024, 0, stream>>>(epack, bcnt, offs, invd, esrc, N);

    // layer 1 agg (XCD-sliced) + fused [L1 GEMM -> L2 projection]
    agg_slice<0><<<ga, THREADS, 0, stream>>>(ab1, esrc, offs, invd, nullptr,
                                             nullptr, ab1, N);
    gemm_fused<128, 2, true><<<gb, 256, 0, stream>>>(ab1, Pb1, b1, Pb2, nullptr, hwroot, N);
    // layer 2 gather (XCD-sliced) + epilogue
    agg_slice<1><<<ga, THREADS, 0, stream>>>(hwroot, esrc, offs, invd, b2,
                                             hwroot, z, N);
    // fused decoder [dec1 -> dec2]
    gemm_fused<64, 1, false><<<gb, 256, 0, stream>>>(z, Pd1, db1, Pd2, db2, out, N);
}

// Round 8
// 203.174 us; speedup vs baseline: 2.4285x; 1.4636x over previous
//
#include <hip/hip_runtime.h>
#include <hip/hip_bf16.h>

// GraphAE: pseudo == 0 => only W[0] of the 8 spline matrices matters.
// Linearization: mean(h[src])@W2_0 == mean(h[src]@W2_0) -> project before gather.
// Round 17 (= R16 resubmit; bench infra failed, kernel never ran):
//  - R15 sliced aggs reverted (244MB HBM fetch: 64B-line amplification).
//    Aggs back to R13 row-gather form.
//  - CSR atomic-serialization fix (partition+fill ~95us inferred):
//    (a) all LDS histograms sub-bucketed [b][4] with sub=tid&3 -> 4x fewer
//        same-address collisions;
//    (b) rank-capture: pass-1 atomicAdd return value = rank within (b,sub);
//        write pos = base + prefix(b,sub) + rank after one LDS scan.
//        Deletes the second (cursor) atomic pass entirely: 1 atomic/edge
//        4-way-spread, was 2/edge unspread.
//
// Verified MFMA layouts (guide §3): A[m=lane&15][k=(lane>>4)*8+j],
// B[k=(lane>>4)*8+j][n=lane&15], D[row=(lane>>4)*4+r][col=lane&15].

#define THREADS 256

typedef __attribute__((ext_vector_type(8))) short bf16x8;   // 8 bf16 = 4 VGPRs
typedef __attribute__((ext_vector_type(4))) float f32x4;    // acc

__device__ __forceinline__ float bf2f(unsigned short u) {
    unsigned v = ((unsigned)u) << 16;
    return __builtin_bit_cast(float, v);
}
__device__ __forceinline__ unsigned short f2bf(float f) {
    __hip_bfloat16 h = __float2bfloat16(f);   // RNE
    return __builtin_bit_cast(unsigned short, h);
}
__device__ __forceinline__ void acc8(float* f, uint4 v) {
    f[0] += bf2f((unsigned short)v.x); f[1] += bf2f((unsigned short)(v.x >> 16));
    f[2] += bf2f((unsigned short)v.y); f[3] += bf2f((unsigned short)(v.y >> 16));
    f[4] += bf2f((unsigned short)v.z); f[5] += bf2f((unsigned short)(v.z >> 16));
    f[6] += bf2f((unsigned short)v.w); f[7] += bf2f((unsigned short)(v.w >> 16));
}

// ---------------- weight pack ----------------
// Pack fp32 W (eff. K x NOUT) into MFMA B-frag layout bf16:
// dst[(((s*NB + j)*64 + lane)*8 + i] = W[s*32 + (lane>>4)*8 + i][j*16 + (lane&15)]
__device__ __forceinline__ void pack_one(unsigned short* dst,
                                         const float* W0, const float* W1,
                                         int NB, int ksplit, int colsplit,
                                         int ld0, int ld1, int t) {
    int i = t & 7, lane = (t >> 3) & 63, rest = t >> 9;
    int j = rest % NB, s = rest / NB;
    int k = s * 32 + ((lane >> 4) << 3) + i;
    int c = (j << 4) + (lane & 15);
    float v;
    if (c >= colsplit)    v = W1[(size_t)k * ld1 + (c - colsplit)];
    else if (k >= ksplit) v = W1[(size_t)(k - ksplit) * ld1 + c];
    else                  v = W0[(size_t)k * ld0 + c];
    dst[t] = f2bf(v);
}

#define BIG (1 << 30)

// prep: weight packs + x->bf16 (vectorized) + bucket histogram (sub-bucketed)
__global__ void prep_kernel(const float* __restrict__ W1g, const float* __restrict__ root1,
                            const float* __restrict__ W2g, const float* __restrict__ root2,
                            const float* __restrict__ dw1, const float* __restrict__ dw2,
                            const float* __restrict__ x, const int* __restrict__ dstv,
                            int* __restrict__ bcnt,
                            unsigned short* __restrict__ Pb1,   // 128x256
                            unsigned short* __restrict__ Pb2,   // 256x128
                            unsigned short* __restrict__ Pd1,   // 64x256
                            unsigned short* __restrict__ Pd2,   // 256x64
                            unsigned short* __restrict__ ab1,   // N x 128, x -> cols 64:128
                            int n, int E, int pb_pack) {
    if ((int)blockIdx.x >= pb_pack) {
        __shared__ int hist[1024];           // [bucket][sub]
        int t = threadIdx.x;
        hist[t] = 0; hist[t + 256] = 0; hist[t + 512] = 0; hist[t + 768] = 0;
        __syncthreads();
        int e0 = ((int)blockIdx.x - pb_pack) * 4096;
        int sub = t & 3;
#pragma unroll
        for (int i = 0; i < 16; ++i) {
            int e = e0 + t + i * 256;
            if (e < E) atomicAdd(&hist[((dstv[e] >> 8) << 2) | sub], 1);
        }
        __syncthreads();
        int h = hist[t * 4] + hist[t * 4 + 1] + hist[t * 4 + 2] + hist[t * 4 + 3];
        if (h) atomicAdd(&bcnt[t], h);
        return;
    }
    int t = blockIdx.x * blockDim.x + threadIdx.x;
    if (t < 32768) {
        pack_one(Pb1, W1g, root1, 16, 64, BIG, 256, 256, t);
    } else if (t < 65536) {
        pack_one(Pb2, W2g, root2, 8, BIG, 64, 64, 64, t - 32768);
    } else if (t < 81920) {
        pack_one(Pd1, dw1, dw1, 16, BIG, BIG, 256, 256, t - 65536);
    } else if (t < 98304) {
        pack_one(Pd2, dw2, dw2, 4, BIG, BIG, 64, 64, t - 81920);
    } else if (t < 98304 + n * 16) {
        int u = t - 98304;
        int row = u >> 4, c4 = (u & 15) * 4;
        float4 v = *(const float4*)(x + (size_t)row * 64 + c4);
        unsigned lo = (unsigned)f2bf(v.x) | ((unsigned)f2bf(v.y) << 16);
        unsigned hi = (unsigned)f2bf(v.z) | ((unsigned)f2bf(v.w) << 16);
        uint2 o; o.x = lo; o.y = hi;
        *(uint2*)(ab1 + (size_t)row * 128 + 64 + c4) = o;
    }
}

// Pass A: partition edges into buckets of 256 consecutive dst nodes.
// 512 thr x 2048 edges/block. Sub-bucketed hist + rank-capture: one
// atomicAdd per edge (4-way spread); position from scanned prefix + rank.
__global__ __launch_bounds__(512) void partition_edges(
    const int* __restrict__ src, const int* __restrict__ dst,
    const int* __restrict__ bcnt, int* __restrict__ bcur,
    int* __restrict__ epack, int E) {
    __shared__ int h4[1024];     // [bucket][sub] counts
    __shared__ int s4[1024];     // inclusive scan of h4
    __shared__ int base[256];    // global write base (minus bucket-exclusive)
    __shared__ int bb[256];
    int t = threadIdx.x;
    h4[t] = 0; h4[t + 512] = 0;
    __syncthreads();
    int e0 = blockIdx.x * 2048;
    int sub = t & 3;
    int myd[4], mys[4], myr[4];
#pragma unroll
    for (int i = 0; i < 4; ++i) {
        int e = e0 + t + i * 512;
        int d = (e < E) ? dst[e] : -1;
        mys[i] = (e < E) ? src[e] : 0;
        myd[i] = d;
        if (d >= 0) myr[i] = atomicAdd(&h4[((d >> 8) << 2) | sub], 1);
    }
    __syncthreads();
    s4[t] = h4[t]; s4[t + 512] = h4[t + 512];
    __syncthreads();
    for (int off = 1; off < 1024; off <<= 1) {
        int v0 = (t >= off) ? s4[t - off] : 0;
        int v1 = (t + 512 >= off) ? s4[t + 512 - off] : 0;
        __syncthreads();
        s4[t] += v0; s4[t + 512] += v1;
        __syncthreads();
    }
    // bucket global bases: exclusive scan of bcnt + per-bucket cursor
    int cb = 0;
    if (t < 256) { cb = bcnt[t]; bb[t] = cb; }
    __syncthreads();
    for (int off = 1; off < 256; off <<= 1) {
        int xv = (t >= off && t < 256) ? bb[t - off] : 0;
        __syncthreads();
        if (t < 256) bb[t] += xv;
        __syncthreads();
    }
    if (t < 256) {
        int lo = t ? s4[t * 4 - 1] : 0;           // block-local bucket-exclusive
        int h = s4[t * 4 + 3] - lo;               // block's count for bucket t
        if (h > 0)
            base[t] = (bb[t] - cb) + atomicAdd(&bcur[t], h) - lo;
    }
    __syncthreads();
#pragma unroll
    for (int i = 0; i < 4; ++i) {
        int d = myd[i];
        if (d >= 0) {
            int b = d >> 8;
            int flat = (b << 2) | sub;
            int pre = flat ? s4[flat - 1] : 0;
            epack[base[b] + pre + myr[i]] = ((d & 255) << 20) | mys[i];
        }
    }
}

// Pass B: one block (1024 thr) per 256-node bucket. Sub-bucketed per-node
// hist + rank-capture (rank stored in LDS rk[], indexed by item), one scan,
// direct grouped esrc write. Fallback to cursor atomics if ecount > 8192.
__global__ __launch_bounds__(1024) void bucket_fill2(
    const int* __restrict__ epack, const int* __restrict__ bcnt,
    int* __restrict__ offs, float* __restrict__ invd,
    int* __restrict__ esrc, int N) {
    __shared__ int sb_[256];
    __shared__ int n4[1024];     // [node][sub] counts -> inclusive scan
    __shared__ int ncur[256];    // fallback cursors
    __shared__ int rk[8192];     // per-item rank
    int b = blockIdx.x, t = threadIdx.x;
    int n0 = b << 8;
    int cb = 0;
    if (t < 256) { cb = bcnt[t]; sb_[t] = cb; }
    __syncthreads();
    for (int off = 1; off < 256; off <<= 1) {
        int xv = (t >= off && t < 256) ? sb_[t - off] : 0;
        __syncthreads();
        if (t < 256) sb_[t] += xv;
        __syncthreads();
    }
    int ebase = b ? sb_[b - 1] : 0;
    int ecount = sb_[b] - ebase;
    if (b == 0 && t == 0) offs[N] = sb_[255];
    n4[t] = 0;
    __syncthreads();
    bool useRk = (ecount <= 8192);
    int sub = t & 3;
    for (int i = t; i < ecount; i += 1024) {
        int dl = epack[ebase + i] >> 20;
        int r = atomicAdd(&n4[(dl << 2) | sub], 1);
        if (useRk) rk[i] = r;
    }
    __syncthreads();
    // inclusive scan of n4[1024]
    for (int off = 1; off < 1024; off <<= 1) {
        int xv = (t >= off) ? n4[t - off] : 0;
        __syncthreads();
        n4[t] += xv;
        __syncthreads();
    }
    if (t < 256) {
        int lo = t ? n4[t * 4 - 1] : 0;           // node-exclusive within bucket
        int v = n4[t * 4 + 3] - lo;               // node degree
        int node = n0 + t;
        if (node < N) {
            offs[node] = ebase + lo;
            invd[node] = 1.0f / (float)max(v, 1);
        }
        ncur[t] = 0;
    }
    __syncthreads();
    if (useRk) {
        for (int i = t; i < ecount; i += 1024) {
            int p = epack[ebase + i];
            int dl = p >> 20;
            int flat = (dl << 2) | (i & 3);       // sub == i&3 (stride 1024)
            int pre = flat ? n4[flat - 1] : 0;
            esrc[ebase + pre + rk[i]] = p & 0xFFFFF;
        }
    } else {
        for (int i = t; i < ecount; i += 1024) {
            int p = epack[ebase + i];
            int dl = p >> 20;
            int lo = dl ? n4[dl * 4 - 1] : 0;
            int pos = atomicAdd(&ncur[dl], 1);
            esrc[ebase + lo + pos] = p & 0xFFFFF;
        }
    }
}

// ---------------- gathers: 16B/lane, 8 edges per wave-instr, 16-edge unroll ----
// lane = slot(8) x c(8); lane loads features [c*8, c*8+8) of edge (j+slot).
// agg1 = mean(x[src]): reads ab1 cols 64:128, writes ab1 cols 0:64.
__global__ void agg_x4(unsigned short* __restrict__ ab1, const int* __restrict__ esrc,
                       const int* __restrict__ offs, const float* __restrict__ invd,
                       int n) {
    int node = blockIdx.x * 4 + (threadIdx.x >> 6);
    if (node >= n) return;
    int l = threadIdx.x & 63;
    int slot = l >> 3, c = l & 7;
    const unsigned short* xb = ab1 + 64 + c * 8;
    int s = offs[node], e = offs[node + 1];
    float a0[8] = {}, a1[8] = {};
    int j = s;
    for (; j + 16 <= e; j += 16) {
        int i0 = esrc[j + slot], i1 = esrc[j + 8 + slot];
        uint4 v0 = *(const uint4*)(xb + (size_t)i0 * 128);
        uint4 v1 = *(const uint4*)(xb + (size_t)i1 * 128);
        acc8(a0, v0); acc8(a1, v1);
    }
    if (j + 8 <= e) {
        int i0 = esrc[j + slot];
        uint4 v0 = *(const uint4*)(xb + (size_t)i0 * 128);
        acc8(a0, v0);
        j += 8;
    }
    if (slot < e - j) {
        int i0 = esrc[j + slot];
        uint4 v0 = *(const uint4*)(xb + (size_t)i0 * 128);
        acc8(a1, v0);
    }
    float r[8];
#pragma unroll
    for (int k = 0; k < 8; ++k) {
        r[k] = a0[k] + a1[k];
        r[k] += __shfl_xor(r[k], 8);
        r[k] += __shfl_xor(r[k], 16);
        r[k] += __shfl_xor(r[k], 32);
    }
    if (slot == 0) {
        float iv = invd[node];
        unsigned p0 = (unsigned)f2bf(r[0] * iv) | ((unsigned)f2bf(r[1] * iv) << 16);
        unsigned p1 = (unsigned)f2bf(r[2] * iv) | ((unsigned)f2bf(r[3] * iv) << 16);
        unsigned p2 = (unsigned)f2bf(r[4] * iv) | ((unsigned)f2bf(r[5] * iv) << 16);
        unsigned p3 = (unsigned)f2bf(r[6] * iv) | ((unsigned)f2bf(r[7] * iv) << 16);
        uint4 o; o.x = p0; o.y = p1; o.z = p2; o.w = p3;
        *(uint4*)(ab1 + (size_t)node * 128 + c * 8) = o;
    }
}

// z = mean(hw[src]) + hroot + b2 ; hwroot N x 128 bf16 (0:64 hw, 64:128 hroot)
__global__ void agg_z4(const unsigned short* __restrict__ hwroot,
                       const int* __restrict__ esrc, const int* __restrict__ offs,
                       const float* __restrict__ invd, const float* __restrict__ b2,
                       unsigned short* __restrict__ z, int n) {
    int node = blockIdx.x * 4 + (threadIdx.x >> 6);
    if (node >= n) return;
    int l = threadIdx.x & 63;
    int slot = l >> 3, c = l & 7;
    const unsigned short* hb = hwroot + c * 8;
    int s = offs[node], e = offs[node + 1];
    float a0[8] = {}, a1[8] = {};
    int j = s;
    for (; j + 16 <= e; j += 16) {
        int i0 = esrc[j + slot], i1 = esrc[j + 8 + slot];
        uint4 v0 = *(const uint4*)(hb + (size_t)i0 * 128);
        uint4 v1 = *(const uint4*)(hb + (size_t)i1 * 128);
        acc8(a0, v0); acc8(a1, v1);
    }
    if (j + 8 <= e) {
        int i0 = esrc[j + slot];
        uint4 v0 = *(const uint4*)(hb + (size_t)i0 * 128);
        acc8(a0, v0);
        j += 8;
    }
    if (slot < e - j) {
        int i0 = esrc[j + slot];
        uint4 v0 = *(const uint4*)(hb + (size_t)i0 * 128);
        acc8(a1, v0);
    }
    float r[8];
#pragma unroll
    for (int k = 0; k < 8; ++k) {
        r[k] = a0[k] + a1[k];
        r[k] += __shfl_xor(r[k], 8);
        r[k] += __shfl_xor(r[k], 16);
        r[k] += __shfl_xor(r[k], 32);
    }
    if (slot == 0) {
        float iv = invd[node];
        uint4 hr = *(const uint4*)(hwroot + (size_t)node * 128 + 64 + c * 8);
        float4 bA = *(const float4*)(b2 + c * 8);
        float4 bB = *(const float4*)(b2 + c * 8 + 4);
        float v0 = r[0] * iv + bf2f((unsigned short)hr.x) + bA.x;
        float v1 = r[1] * iv + bf2f((unsigned short)(hr.x >> 16)) + bA.y;
        float v2 = r[2] * iv + bf2f((unsigned short)hr.y) + bA.z;
        float v3 = r[3] * iv + bf2f((unsigned short)(hr.y >> 16)) + bA.w;
        float v4 = r[4] * iv + bf2f((unsigned short)hr.z) + bB.x;
        float v5 = r[5] * iv + bf2f((unsigned short)(hr.z >> 16)) + bB.y;
        float v6 = r[6] * iv + bf2f((unsigned short)hr.w) + bB.z;
        float v7 = r[7] * iv + bf2f((unsigned short)(hr.w >> 16)) + bB.w;
        unsigned p0 = (unsigned)f2bf(v0) | ((unsigned)f2bf(v1) << 16);
        unsigned p1 = (unsigned)f2bf(v2) | ((unsigned)f2bf(v3) << 16);
        unsigned p2 = (unsigned)f2bf(v4) | ((unsigned)f2bf(v5) << 16);
        unsigned p3 = (unsigned)f2bf(v6) | ((unsigned)f2bf(v7) << 16);
        uint4 o; o.x = p0; o.y = p1; o.z = p2; o.w = p3;
        *(uint4*)(z + (size_t)node * 64 + c * 8) = o;
    }
}

// ---------------- fused double-GEMM ----------------
// Stage 1: T = relu(A @ Wp1 + bias1)  (A: n x K1 bf16, T: 64 x 256 tile in LDS)
// Stage 2: C = T @ Wp2 (+ bias2)      (C: n x (NBW2*64))
template <int K1, int NBW2, bool OUTBF>
__global__ __launch_bounds__(256) void gemm_fused(
    const unsigned short* __restrict__ A,
    const unsigned short* __restrict__ Bp1, const float* __restrict__ bias1,
    const unsigned short* __restrict__ Bp2, const float* __restrict__ bias2,
    void* __restrict__ Cv, int n)
{
    constexpr int KS1 = K1 / 32;
    constexpr int N2 = NBW2 * 64;
    constexpr int NB2 = NBW2 * 4;
    __shared__ unsigned short ht[64][264];

    const int m0 = blockIdx.x * 64;
    const int lane = threadIdx.x & 63;
    const int w = threadIdx.x >> 6;
    const int quad = lane >> 4;
    const int l16 = lane & 15;

    // ---- stage 1 ----
    {
        f32x4 acc[4][4] = {};
        const unsigned short* Arow = A + (size_t)(m0 + l16) * K1 + quad * 8;
        for (int s = 0; s < KS1; ++s) {
            bf16x8 a[4];
#pragma unroll
            for (int mb = 0; mb < 4; ++mb)
                a[mb] = *(const bf16x8*)(Arow + (size_t)mb * 16 * K1 + s * 32);
#pragma unroll
            for (int jn = 0; jn < 4; ++jn) {
                int j = w * 4 + jn;
                bf16x8 b = *(const bf16x8*)(Bp1 + ((size_t)(s * 16 + j) * 64 + lane) * 8);
#pragma unroll
                for (int mb = 0; mb < 4; ++mb)
                    acc[mb][jn] = __builtin_amdgcn_mfma_f32_16x16x32_bf16(a[mb], b, acc[mb][jn], 0, 0, 0);
            }
        }
#pragma unroll
        for (int jn = 0; jn < 4; ++jn) {
            int col = (w * 4 + jn) * 16 + l16;
            float bv = bias1[col];
#pragma unroll
            for (int mb = 0; mb < 4; ++mb)
#pragma unroll
                for (int r = 0; r < 4; ++r) {
                    int row = mb * 16 + quad * 4 + r;
                    ht[row][col] = f2bf(fmaxf(acc[mb][jn][r] + bv, 0.f));
                }
        }
    }
    __syncthreads();

    // ---- stage 2 ----
    {
        f32x4 acc[4][NBW2] = {};
        for (int s = 0; s < 8; ++s) {
            bf16x8 a[4];
#pragma unroll
            for (int mb = 0; mb < 4; ++mb)
                a[mb] = *(const bf16x8*)&ht[mb * 16 + l16][s * 32 + quad * 8];
#pragma unroll
            for (int jn = 0; jn < NBW2; ++jn) {
                int j = w * NBW2 + jn;
                bf16x8 b = *(const bf16x8*)(Bp2 + ((size_t)(s * NB2 + j) * 64 + lane) * 8);
#pragma unroll
                for (int mb = 0; mb < 4; ++mb)
                    acc[mb][jn] = __builtin_amdgcn_mfma_f32_16x16x32_bf16(a[mb], b, acc[mb][jn], 0, 0, 0);
            }
        }
#pragma unroll
        for (int jn = 0; jn < NBW2; ++jn) {
            int col = (w * NBW2 + jn) * 16 + l16;
            float bv = bias2 ? bias2[col] : 0.f;
#pragma unroll
            for (int mb = 0; mb < 4; ++mb)
#pragma unroll
                for (int r = 0; r < 4; ++r) {
                    int row = m0 + mb * 16 + quad * 4 + r;
                    if (row < n) {
                        float v = acc[mb][jn][r] + bv;
                        if (OUTBF)
                            ((unsigned short*)Cv)[(size_t)row * N2 + col] = f2bf(v);
                        else
                            ((float*)Cv)[(size_t)row * N2 + col] = v;
                    }
                }
        }
    }
}

extern "C" void kernel_launch(void* const* d_in, const int* in_sizes, int n_in,
                              void* d_out, int out_size, void* d_ws, size_t ws_size,
                              hipStream_t stream) {
    const float* x      = (const float*)d_in[0];
    const int*   ei     = (const int*)d_in[1];
    const float* W1g    = (const float*)d_in[2];   // (8,64,256): [0] = first 16384
    const float* root1  = (const float*)d_in[3];
    const float* b1     = (const float*)d_in[4];
    const float* W2g    = (const float*)d_in[5];   // (8,256,64): [0] = first 16384
    const float* root2  = (const float*)d_in[6];
    const float* b2     = (const float*)d_in[7];
    const float* dw1    = (const float*)d_in[8];
    const float* db1    = (const float*)d_in[9];
    const float* dw2    = (const float*)d_in[10];
    const float* db2    = (const float*)d_in[11];
    float* out = (float*)d_out;

    const int N = in_sizes[0] / 64;
    const int E = in_sizes[1] / 2;
    const int Npad = N + 64;
    const int* srcv = ei;
    const int* dstv = ei + E;

    char* ws = (char*)d_ws;
    auto alloc = [&](size_t bytes) -> void* {
        void* p = (void*)ws;
        ws += (bytes + 255) & ~(size_t)255;
        return p;
    };
    int*   bcnt   = (int*)alloc(1024);               // per-bucket counts (256)
    int*   bcur   = (int*)alloc(1024);               // 0-based bucket cursors
    int*   offs   = (int*)alloc((size_t)(N + 1) * 4);
    float* invd   = (float*)alloc((size_t)N * 4);
    int*   esrc   = (int*)alloc((size_t)E * 4);
    int*   epack  = (int*)alloc((size_t)E * 4);
    unsigned short* Pb1 = (unsigned short*)alloc(32768 * 2);
    unsigned short* Pb2 = (unsigned short*)alloc(32768 * 2);
    unsigned short* Pd1 = (unsigned short*)alloc(16384 * 2);
    unsigned short* Pd2 = (unsigned short*)alloc(16384 * 2);
    unsigned short* ab1    = (unsigned short*)alloc((size_t)Npad * 128 * 2);  // [agg1 | xb]
    unsigned short* hwroot = (unsigned short*)alloc((size_t)Npad * 128 * 2);
    unsigned short* z      = (unsigned short*)alloc((size_t)Npad * 64 * 2);

    hipMemsetAsync(bcnt, 0, 2048, stream);           // bcnt + bcur (adjacent)

    int gb = (N + 63) / 64;
    int nbkt = (N + 255) / 256;
    int pa = (E + 4095) / 4096;                      // prep hist blocks
    int pa2 = (E + 2047) / 2048;                     // partition blocks
    int pb_pack = (98304 + N * 16 + THREADS - 1) / THREADS;

    // packs + x->bf16 + bucket histogram (one kernel, disjoint block ranges)
    prep_kernel<<<pb_pack + pa, THREADS, 0, stream>>>(
        W1g, root1, W2g, root2, dw1, dw2, x, dstv, bcnt,
        Pb1, Pb2, Pd1, Pd2, ab1, N, E, pb_pack);
    // bucket-level CSR (bases computed locally from bcnt in each kernel)
    partition_edges<<<pa2, 512, 0, stream>>>(srcv, dstv, bcnt, bcur, epack, E);
    bucket_fill2<<<nbkt, 1024, 0, stream>>>(epack, bcnt, offs, invd, esrc, N);

    // layer 1 agg + fused [L1 GEMM -> L2 projection]
    agg_x4<<<(N + 3) / 4, THREADS, 0, stream>>>(ab1, esrc, offs, invd, N);
    gemm_fused<128, 2, true><<<gb, 256, 0, stream>>>(ab1, Pb1, b1, Pb2, nullptr, hwroot, N);
    // layer 2 gather + epilogue
    agg_z4<<<(N + 3) / 4, THREADS, 0, stream>>>(hwroot, esrc, offs, invd, b2, z, N);
    // fused decoder [dec1 -> dec2]
    gemm_fused<64, 1, false><<<gb, 256, 0, stream>>>(z, Pd1, db1, Pd2, db2, out, N);
}